// Round 6
// baseline (232.992 us; speedup 1.0000x reference)
//
#include <hip/hip_runtime.h>
#include <math.h>

#define BATCH 64
#define LSEQ 2048
#define DMOD 256
#define KC 32
#define LCHUNK 128  // l's per block -> 1024 blocks
#define NCH 16      // chunks per b
#define LS 32       // l's per subtile
#define NSUB 4
#define PD 264  // sRev pitch (bf16): 528B rows, 16B-aligned
#define PT 40   // sRevT pitch (bf16): 80B rows, 16B-aligned
#define PP 36   // sP pitch (bf16): 72B rows, 8B-aligned

typedef __bf16 bf16x4 __attribute__((ext_vector_type(4)));
typedef __bf16 bf16x8 __attribute__((ext_vector_type(8)));
typedef float f32x4 __attribute__((ext_vector_type(4)));

union FragU {
  uint4 u;
  uint2 h[2];
  bf16x8 b;
};

// One block: (b, 128-l chunk). C_u[32 k][256 d] = sum_l exp(s[l,k])*rev[l,d],
// Z[32 k] = sum_l exp(s[l,k]). No max subtraction (|s| <~ 7, exp <= ~1100).
// DIAGNOSTIC: rep loop does identical work twice, writing the SAME region with
// the SAME values both times (deterministic, ws-bounded), to push this
// dispatch above the 78 us harness fills so rocprof shows its counter row.
__global__ __launch_bounds__(256, 4) void fused_pool_kernel(
    const float* __restrict__ rev, const float* __restrict__ W,
    float* __restrict__ cPartial, float* __restrict__ zPartial) {
  __shared__ __align__(16) __bf16 sRev[LS * PD];    // rev[l][d], d-fast (16.9 KB)
  __shared__ __align__(16) __bf16 sRevT[DMOD * PT]; // rev[d][l], l-fast (20.5 KB)
  __shared__ __align__(16) __bf16 sP[KC * PP];      // p[k][l],  l-fast (2.3 KB)
  __shared__ float sZw[4][16];

  const int tid = threadIdx.x;
  const int b = blockIdx.y;
  const int lc = blockIdx.x;
  const int lbase = lc * LCHUNK;
  const int lane = tid & 63;
  const int wave = tid >> 6;
  const int col = lane & 15;
  const int quad = lane >> 4;
  const int Mt = wave & 1;   // GEMM1: l-half; GEMM2: k-half
  const int Nt = wave >> 1;  // GEMM1: k-half; GEMM2: d-128-group
  const int tp = tid & 127;  // transpose: d-pair index (d = 2*tp, 2*tp+1)
  const int th = tid >> 7;   // transpose: l-half (l in [16*th, 16*th+16))

  // ---- W B-frags -> registers, once per block ----
  bf16x8 wfrag[8];
  {
    const float* wrow = W + (Nt * 16 + col) * DMOD + quad * 8;
#pragma unroll
    for (int ks = 0; ks < 8; ++ks) {
      float4 a = *(const float4*)(wrow + ks * 32);
      float4 c = *(const float4*)(wrow + ks * 32 + 4);
      bf16x8 f = {(__bf16)a.x, (__bf16)a.y, (__bf16)a.z, (__bf16)a.w,
                  (__bf16)c.x, (__bf16)c.y, (__bf16)c.z, (__bf16)c.w};
      wfrag[ks] = f;
    }
  }

  for (int rep = 0; rep < 2; ++rep) {
    f32x4 acc2[8];
#pragma unroll
    for (int i = 0; i < 8; ++i) acc2[i] = (f32x4){0.f, 0.f, 0.f, 0.f};
    float zl = 0.f;

    // ---- prologue: stage sub 0 ----
#pragma unroll
    for (int i = 0; i < 8; ++i) {
      int slot = tid + 256 * i;
      int r = slot >> 6, c4 = slot & 63;
      float4 v = *(const float4*)(rev + ((size_t)b * LSEQ + lbase + r) * DMOD + c4 * 4);
      bf16x4 hh = {(__bf16)v.x, (__bf16)v.y, (__bf16)v.z, (__bf16)v.w};
      *(bf16x4*)(&sRev[r * PD + c4 * 4]) = hh;
    }
    __syncthreads();  // beta0: sRev(0) visible; also orders vs prev rep

    for (int sub = 0; sub < NSUB; ++sub) {
      // ======== Phase 1: transpose + GEMM1 + exp/sP (reads sRev) ========
#pragma unroll
      for (int s2 = 0; s2 < 2; ++s2) {
        uint tmp[8];
#pragma unroll
        for (int j = 0; j < 8; ++j) {
          int ll = 16 * th + 8 * s2 + j;
          tmp[j] = *(const uint*)(&sRev[ll * PD + 2 * tp]);
        }
        uint lo[4], hi[4];
#pragma unroll
        for (int i = 0; i < 4; ++i) {
          lo[i] = (tmp[2 * i] & 0xffffu) | (tmp[2 * i + 1] << 16);
          hi[i] = (tmp[2 * i] >> 16) | (tmp[2 * i + 1] & 0xffff0000u);
        }
        uint4 vlo = {lo[0], lo[1], lo[2], lo[3]};
        uint4 vhi = {hi[0], hi[1], hi[2], hi[3]};
        *(uint4*)(&sRevT[(2 * tp) * PT + 16 * th + 8 * s2]) = vlo;
        *(uint4*)(&sRevT[(2 * tp + 1) * PT + 16 * th + 8 * s2]) = vhi;
      }

      // GEMM1: C1[l][k] (Mt l-half x Nt k-half), K=256
      f32x4 acc1 = {0.f, 0.f, 0.f, 0.f};
#pragma unroll
      for (int ks = 0; ks < 8; ++ks) {
        FragU af;
        af.u = *(const uint4*)(&sRev[(Mt * 16 + col) * PD + ks * 32 + quad * 8]);
        acc1 = __builtin_amdgcn_mfma_f32_16x16x32_bf16(af.b, wfrag[ks], acc1, 0, 0, 0);
      }
      // C1: row(m=l)=quad*4+reg, col(n=k)=col. exp -> sP[k][l] as one b64
      {
        bf16x4 ph;
#pragma unroll
        for (int reg = 0; reg < 4; ++reg) {
          float p = __expf(acc1[reg]);
          ph[reg] = (__bf16)p;
          zl += (float)ph[reg];
        }
        *(bf16x4*)(&sP[(Nt * 16 + col) * PP + Mt * 16 + quad * 4]) = ph;
      }
      __syncthreads();  // alpha: sRevT + sP visible; sRev free to overwrite

      // ======== Phase 2: GEMM2 + stage(sub+1) ========
      FragU pa;
      pa.h[0] = *(const uint2*)(&sP[(Mt * 16 + col) * PP + quad * 8]);
      pa.h[1] = *(const uint2*)(&sP[(Mt * 16 + col) * PP + quad * 8 + 4]);
#pragma unroll
      for (int nt = 0; nt < 8; ++nt) {
        int d = (Nt * 8 + nt) * 16 + col;
        FragU bb;
        bb.u = *(const uint4*)(&sRevT[d * PT + quad * 8]);
        acc2[nt] = __builtin_amdgcn_mfma_f32_16x16x32_bf16(pa.b, bb.b, acc2[nt], 0, 0, 0);
      }
      if (sub + 1 < NSUB) {
        const int l1 = lbase + (sub + 1) * LS;
#pragma unroll
        for (int i = 0; i < 8; ++i) {
          int slot = tid + 256 * i;
          int r = slot >> 6, c4 = slot & 63;
          float4 v = *(const float4*)(rev + ((size_t)b * LSEQ + l1 + r) * DMOD + c4 * 4);
          bf16x4 hh = {(__bf16)v.x, (__bf16)v.y, (__bf16)v.z, (__bf16)v.w};
          *(bf16x4*)(&sRev[r * PD + c4 * 4]) = hh;
        }
        __syncthreads();  // beta: sRev(sub+1) visible; sRevT/sP free
      }
    }

    // ---- epilogue: Z reduce + partial stores (same dest both reps) ----
    float zz = zl;
    zz += __shfl_xor(zz, 16, 64);
    zz += __shfl_xor(zz, 32, 64);
    if (quad == 0) sZw[wave][col] = zz;
    __syncthreads();
    if (tid < KC) {
      int Ntt = tid >> 4, c = tid & 15;
      zPartial[((size_t)b * NCH + lc) * KC + tid] = sZw[2 * Ntt][c] + sZw[2 * Ntt + 1][c];
    }
    float* dst = cPartial + (((size_t)b * NCH + lc) * KC) * DMOD;
#pragma unroll
    for (int nt = 0; nt < 8; ++nt) {
      int d = (Nt * 8 + nt) * 16 + col;
#pragma unroll
      for (int reg = 0; reg < 4; ++reg) {
        int k = Mt * 16 + quad * 4 + reg;
        dst[k * DMOD + d] = acc2[nt][reg];
      }
    }
    __syncthreads();  // protect sZw/sRevT/sP before next rep re-stages
  }
}

// out[b][k][d] = (sum_lc C_u) / (sum_lc Z), float4-vectorized
__global__ __launch_bounds__(256) void reduce_kernel(
    const float* __restrict__ cPartial, const float* __restrict__ zPartial,
    float* __restrict__ out) {
  int idx = blockIdx.x * 256 + threadIdx.x;  // 131072 float4 slots
  int b = idx >> 11;
  int k = (idx >> 6) & 31;
  float4 s = {0.f, 0.f, 0.f, 0.f};
  float z = 0.f;
#pragma unroll
  for (int lcc = 0; lcc < NCH; ++lcc) {
    const float4 v = *(const float4*)(cPartial +
                                      ((((size_t)b * NCH + lcc) * KC + k) << 8) +
                                      ((idx & 63) << 2));
    s.x += v.x; s.y += v.y; s.z += v.z; s.w += v.w;
    z += zPartial[((size_t)b * NCH + lcc) * KC + k];
  }
  float zi = 1.0f / z;
  float4 o = {s.x * zi, s.y * zi, s.z * zi, s.w * zi};
  *(float4*)(out + ((size_t)idx << 2)) = o;
}

extern "C" void kernel_launch(void* const* d_in, const int* in_sizes, int n_in,
                              void* d_out, int out_size, void* d_ws,
                              size_t ws_size, hipStream_t stream) {
  const float* rev = (const float*)d_in[0];  // 64*2048*256 fp32
  const float* W = (const float*)d_in[1];    // 32*256 fp32
  float* out = (float*)d_out;                // 64*32*256 fp32

  float* ws = (float*)d_ws;
  // cPartial: 64*16*32*256 floats (32 MiB); zPartial: 64*16*32 floats (128 KiB)
  float* cPartial = ws;
  float* zPartial = cPartial + (size_t)BATCH * NCH * KC * DMOD;

  fused_pool_kernel<<<dim3(NCH, BATCH), dim3(256), 0, stream>>>(rev, W, cPartial,
                                                                zPartial);
  reduce_kernel<<<dim3(512), dim3(256), 0, stream>>>(cPartial, zPartial, out);
}

// Round 7
// 197.076 us; speedup vs baseline: 1.1822x; 1.1822x over previous
//
#include <hip/hip_runtime.h>
#include <math.h>

#define BATCH 64
#define LSEQ 2048
#define DMOD 256
#define KC 32
#define LCH 256  // l's per block -> 512 blocks = 2/CU exactly
#define NCH 8    // chunks per b
#define LS 64    // l's per subtile
#define NSUB 4
#define PD 264  // sRev pitch (bf16): 528B rows, 16B-aligned
#define PT 72   // sRevT pitch (bf16): 144B rows, 16B-aligned
#define PP 72   // sP pitch (bf16): 144B rows, 16B-aligned

typedef __bf16 bf16x4 __attribute__((ext_vector_type(4)));
typedef __bf16 bf16x8 __attribute__((ext_vector_type(8)));
typedef float f32x4 __attribute__((ext_vector_type(4)));

union FragU {
  uint4 u;
  uint2 h[2];
  bf16x8 b;
};

// One block: (b, 256-l chunk), 8 waves. C_u[32 k][256 d] = sum_l exp(s)*rev,
// Z[32 k] = sum_l exp(s). No max subtraction (|s| <~ 7, exp <= ~1100).
// 2 barriers per 64-l subtile; GEMM1 one 16x16 tile/wave; GEMM2 4 d-tiles/wave.
__global__ __launch_bounds__(512, 4) void fused_pool_kernel(
    const float* __restrict__ rev, const float* __restrict__ W,
    float* __restrict__ cPartial, float* __restrict__ zPartial) {
  __shared__ __align__(16) __bf16 sRev[LS * PD];    // rev[l][d], d-fast (33.8 KB)
  __shared__ __align__(16) __bf16 sRevT[DMOD * PT]; // rev[d][l], l-fast (36.9 KB)
  __shared__ __align__(16) __bf16 sP[KC * PP];      // p[k][l],  l-fast (4.6 KB)
  __shared__ float sZw[8][16];

  const int tid = threadIdx.x;
  const int b = blockIdx.y;
  const int lc = blockIdx.x;
  const int lbase = lc * LCH;
  const int lane = tid & 63;
  const int wave = tid >> 6;  // 0..7
  const int col = lane & 15;
  const int quad = lane >> 4;
  const int Mt1 = wave & 3;   // GEMM1: l-quarter (16 l)
  const int Nt1 = wave >> 2;  // GEMM1: k-half
  const int Mt2 = wave & 1;   // GEMM2: k-half
  const int Dt = wave >> 1;   // GEMM2: d-64-group (4 d-tiles)
  const int tp = tid & 127;   // transpose: d-pair (d = 2tp, 2tp+1)
  const int th = tid >> 7;    // transpose: l-quarter (16 l)

  // ---- W B-frags -> registers, once per block (k-col = Nt1*16+col) ----
  bf16x8 wfrag[8];
  {
    const float* wrow = W + (Nt1 * 16 + col) * DMOD + quad * 8;
#pragma unroll
    for (int ks = 0; ks < 8; ++ks) {
      float4 a = *(const float4*)(wrow + ks * 32);
      float4 c = *(const float4*)(wrow + ks * 32 + 4);
      bf16x8 f = {(__bf16)a.x, (__bf16)a.y, (__bf16)a.z, (__bf16)a.w,
                  (__bf16)c.x, (__bf16)c.y, (__bf16)c.z, (__bf16)c.w};
      wfrag[ks] = f;
    }
  }

  f32x4 acc2[4];
#pragma unroll
  for (int i = 0; i < 4; ++i) acc2[i] = (f32x4){0.f, 0.f, 0.f, 0.f};
  float zl = 0.f;

  // ---- prologue: stage sub 0 (64 rows x 256 d, fp32 -> bf16) ----
#pragma unroll
  for (int i = 0; i < 8; ++i) {
    int slot = tid + 512 * i;
    int r = slot >> 6, c4 = slot & 63;  // r wave-uniform
    float4 v = *(const float4*)(rev + ((size_t)b * LSEQ + lbase + r) * DMOD + c4 * 4);
    bf16x4 hh = {(__bf16)v.x, (__bf16)v.y, (__bf16)v.z, (__bf16)v.w};
    *(bf16x4*)(&sRev[r * PD + c4 * 4]) = hh;
  }
  __syncthreads();  // beta0: sRev(0) visible

  for (int sub = 0; sub < NSUB; ++sub) {
    // ======== Phase 1: transpose + GEMM1 + exp/sP (reads sRev) ========
#pragma unroll
    for (int s2 = 0; s2 < 2; ++s2) {
      uint tmp[8];
#pragma unroll
      for (int j = 0; j < 8; ++j) {
        int ll = 16 * th + 8 * s2 + j;
        tmp[j] = *(const uint*)(&sRev[ll * PD + 2 * tp]);
      }
      uint lo[4], hi[4];
#pragma unroll
      for (int i = 0; i < 4; ++i) {
        lo[i] = (tmp[2 * i] & 0xffffu) | (tmp[2 * i + 1] << 16);
        hi[i] = (tmp[2 * i] >> 16) | (tmp[2 * i + 1] & 0xffff0000u);
      }
      uint4 vlo = {lo[0], lo[1], lo[2], lo[3]};
      uint4 vhi = {hi[0], hi[1], hi[2], hi[3]};
      *(uint4*)(&sRevT[(2 * tp) * PT + 16 * th + 8 * s2]) = vlo;
      *(uint4*)(&sRevT[(2 * tp + 1) * PT + 16 * th + 8 * s2]) = vhi;
    }

    // GEMM1: C1[l][k] one 16x16 tile (Mt1 l-quarter x Nt1 k-half), K=256
    f32x4 acc1 = {0.f, 0.f, 0.f, 0.f};
#pragma unroll
    for (int ks = 0; ks < 8; ++ks) {
      FragU af;
      af.u = *(const uint4*)(&sRev[(Mt1 * 16 + col) * PD + ks * 32 + quad * 8]);
      acc1 = __builtin_amdgcn_mfma_f32_16x16x32_bf16(af.b, wfrag[ks], acc1, 0, 0, 0);
    }
    // C1: row(m=l)=quad*4+reg, col(n=k)=col. exp -> sP[k][l] as one b64
    {
      bf16x4 ph;
#pragma unroll
      for (int reg = 0; reg < 4; ++reg) {
        float p = __expf(acc1[reg]);
        ph[reg] = (__bf16)p;
        zl += (float)ph[reg];
      }
      *(bf16x4*)(&sP[(Nt1 * 16 + col) * PP + Mt1 * 16 + quad * 4]) = ph;
    }
    __syncthreads();  // alpha: sRevT + sP visible; sRev free to overwrite

    // ======== Phase 2: GEMM2 + stage(sub+1) ========
    // A2[m=k][kd=l] from sP (k-half Mt2), steps s over l; B2 from sRevT.
    FragU pa[2];
#pragma unroll
    for (int s = 0; s < 2; ++s)
      pa[s].u = *(const uint4*)(&sP[(Mt2 * 16 + col) * PP + s * 32 + quad * 8]);
#pragma unroll
    for (int t = 0; t < 4; ++t) {
      int drow = (Dt * 4 + t) * 16 + col;
#pragma unroll
      for (int s = 0; s < 2; ++s) {
        FragU bb;
        bb.u = *(const uint4*)(&sRevT[drow * PT + s * 32 + quad * 8]);
        acc2[t] = __builtin_amdgcn_mfma_f32_16x16x32_bf16(pa[s].b, bb.b, acc2[t], 0, 0, 0);
      }
    }
    if (sub + 1 < NSUB) {
      const int l1 = lbase + (sub + 1) * LS;
#pragma unroll
      for (int i = 0; i < 8; ++i) {
        int slot = tid + 512 * i;
        int r = slot >> 6, c4 = slot & 63;
        float4 v = *(const float4*)(rev + ((size_t)b * LSEQ + l1 + r) * DMOD + c4 * 4);
        bf16x4 hh = {(__bf16)v.x, (__bf16)v.y, (__bf16)v.z, (__bf16)v.w};
        *(bf16x4*)(&sRev[r * PD + c4 * 4]) = hh;
      }
      __syncthreads();  // beta: sRev(sub+1) visible; sRevT/sP free
    }
  }

  // ---- Z: zl is partial for k=Nt1*16+col over wave's l-quarter rows ----
  zl += __shfl_xor(zl, 16, 64);
  zl += __shfl_xor(zl, 32, 64);
  if (quad == 0) sZw[wave][col] = zl;
  __syncthreads();
  if (tid < KC) {
    int h = tid >> 4, c = tid & 15;
    zPartial[((size_t)b * NCH + lc) * KC + tid] =
        sZw[h * 4 + 0][c] + sZw[h * 4 + 1][c] + sZw[h * 4 + 2][c] + sZw[h * 4 + 3][c];
  }

  // ---- store C2 partial: row(m=k)=Mt2*16+quad*4+reg, col(n=d) ----
  float* dst = cPartial + (((size_t)b * NCH + lc) * KC) * DMOD;
#pragma unroll
  for (int t = 0; t < 4; ++t) {
    int d = (Dt * 4 + t) * 16 + col;
#pragma unroll
    for (int reg = 0; reg < 4; ++reg) {
      int k = Mt2 * 16 + quad * 4 + reg;
      dst[k * DMOD + d] = acc2[t][reg];
    }
  }
}

// out[b][k][d] = (sum_lc C_u) / (sum_lc Z), float4-vectorized
__global__ __launch_bounds__(256) void reduce_kernel(
    const float* __restrict__ cPartial, const float* __restrict__ zPartial,
    float* __restrict__ out) {
  int idx = blockIdx.x * 256 + threadIdx.x;  // 131072 float4 slots
  int b = idx >> 11;
  int k = (idx >> 6) & 31;
  float4 s = {0.f, 0.f, 0.f, 0.f};
  float z = 0.f;
#pragma unroll
  for (int lcc = 0; lcc < NCH; ++lcc) {
    const float4 v = *(const float4*)(cPartial +
                                      ((((size_t)b * NCH + lcc) * KC + k) << 8) +
                                      ((idx & 63) << 2));
    s.x += v.x; s.y += v.y; s.z += v.z; s.w += v.w;
    z += zPartial[((size_t)b * NCH + lcc) * KC + k];
  }
  float zi = 1.0f / z;
  float4 o = {s.x * zi, s.y * zi, s.z * zi, s.w * zi};
  *(float4*)(out + ((size_t)idx << 2)) = o;
}

extern "C" void kernel_launch(void* const* d_in, const int* in_sizes, int n_in,
                              void* d_out, int out_size, void* d_ws,
                              size_t ws_size, hipStream_t stream) {
  const float* rev = (const float*)d_in[0];  // 64*2048*256 fp32
  const float* W = (const float*)d_in[1];    // 32*256 fp32
  float* out = (float*)d_out;                // 64*32*256 fp32

  float* ws = (float*)d_ws;
  // cPartial: 64*8*32*256 floats (16 MiB); zPartial: 64*8*32 floats
  float* cPartial = ws;
  float* zPartial = cPartial + (size_t)BATCH * NCH * KC * DMOD;

  fused_pool_kernel<<<dim3(NCH, BATCH), dim3(512), 0, stream>>>(rev, W, cPartial,
                                                                zPartial);
  reduce_kernel<<<dim3(512), dim3(256), 0, stream>>>(cPartial, zPartial, out);
}